// Round 8
// baseline (194.712 us; speedup 1.0000x reference)
//
#include <hip/hip_runtime.h>
#include <math.h>

#pragma clang fp contract(off)

// Problem constants
#define CCH   192            // B*c
#define HW    (512*512)
#define RNUM  8
#define X4_PER_CH (HW / 4)   // 65536 f32x4 per channel
#define SLAB  (X4_PER_CH / 2)// 32768 f32x4 per block (half channel)
#define PT    (SLAB / 256)   // 128 f32x4 per thread
#define NREG  80             // held in registers (320 VGPRs)
#define NLDS  15             // held in LDS (60 KiB)
#define NUNH  (PT - NREG - NLDS) // 33 re-read from cache

typedef float f32x4 __attribute__((ext_vector_type(4)));

// ---------------------------------------------------------------------------
// Un-contractible fp32 RN ops (HIP's __f*_rn are contractable; default
// -ffp-contract fused mul+add in round 1 -> region flips). absmax==0.0
// confirmed rounds 4-7 with these.
// ---------------------------------------------------------------------------
__device__ __forceinline__ float mul_rn(float a, float b) {
    float r; asm volatile("v_mul_f32 %0, %1, %2" : "=v"(r) : "v"(a), "v"(b)); return r;
}
__device__ __forceinline__ float add_rn(float a, float b) {
    float r; asm volatile("v_add_f32 %0, %1, %2" : "=v"(r) : "v"(a), "v"(b)); return r;
}
__device__ __forceinline__ float sub_rn(float a, float b) {
    float r; asm volatile("v_sub_f32 %0, %1, %2" : "=v"(r) : "v"(a), "v"(b)); return r;
}

// region-value select: id = count(b_i <= v), BST of 7 cmp + 7 cndmask.
__device__ __forceinline__ float bst_sel(float v,
    float b0, float b1, float b2, float b3, float b4, float b5, float b6,
    float r0, float r1, float r2, float r3, float r4, float r5, float r6, float r7) {
    return (v < b3) ? ((v < b1) ? ((v < b0) ? r0 : r1)
                                : ((v < b2) ? r2 : r3))
                    : ((v < b5) ? ((v < b4) ? r4 : r5)
                                : ((v < b6) ? r6 : r7));
}

// ---------------------------------------------------------------------------
// Fused single kernel: 2 blocks per channel. Each block loads its half-
// channel ONCE, holding 80 f32x4/thread in registers + 15 in LDS; computes
// half-channel min/max; exchanges with its partner block via ws (per-channel
// atomic counter, pairwise spin); computes params (bit-identical in both
// blocks); transforms held data without re-reading it from memory.
// Pairwise sync is deadlock-free: 192 pairs < 256 co-resident blocks
// (1 block/CU at 512 VGPR), so a complete pair is always resident.
// ---------------------------------------------------------------------------
__global__ __launch_bounds__(256, 1) void k_fused(
        const float* __restrict__ xg,
        const float* __restrict__ region_percentiles,
        const float* __restrict__ proxy_percentiles,
        float* __restrict__ outg,
        int*   __restrict__ cnt,    // ws: per-channel arrival counters (memset 0)
        float* __restrict__ part) { // ws: per-channel {mnA,mxA,mnB,mxB}
    const int tid  = threadIdx.x;
    const int chan = blockIdx.x >> 1;
    const int half = blockIdx.x & 1;

    const f32x4* px = (const f32x4*)xg + (size_t)chan * X4_PER_CH + (size_t)half * SLAB;
    f32x4*       po = (f32x4*)outg     + (size_t)chan * X4_PER_CH + (size_t)half * SLAB;

    __shared__ f32x4 slds[NLDS * 256];   // 60 KiB staging
    __shared__ float smn[256], smx[256]; // 2 KiB reduce
    __shared__ float sprm[16];           // params broadcast

    // ---- phase 1: load once, reduce min/max ----
    f32x4 h[NREG];
    #pragma unroll
    for (int k = 0; k < NREG; ++k) h[k] = px[k * 256 + tid];

    float mn = INFINITY, mx = -INFINITY;
    #pragma unroll
    for (int k = 0; k < NREG; ++k) {
        mn = fminf(mn, fminf(fminf(h[k].x, h[k].y), fminf(h[k].z, h[k].w)));
        mx = fmaxf(mx, fmaxf(fmaxf(h[k].x, h[k].y), fmaxf(h[k].z, h[k].w)));
    }
    #pragma unroll
    for (int j = 0; j < NLDS; ++j) {
        f32x4 t = px[(NREG + j) * 256 + tid];
        mn = fminf(mn, fminf(fminf(t.x, t.y), fminf(t.z, t.w)));
        mx = fmaxf(mx, fmaxf(fmaxf(t.x, t.y), fmaxf(t.z, t.w)));
        slds[j * 256 + tid] = t;
    }
    // unheld tail: loaded LAST so its lines are the newest in L3 at the
    // moment writes begin; re-read FIRST in phase 2.
    #pragma unroll
    for (int j = 0; j < NUNH; ++j) {
        f32x4 t = px[(NREG + NLDS + j) * 256 + tid];
        mn = fminf(mn, fminf(fminf(t.x, t.y), fminf(t.z, t.w)));
        mx = fmaxf(mx, fmaxf(fmaxf(t.x, t.y), fmaxf(t.z, t.w)));
    }

    smn[tid] = mn; smx[tid] = mx;
    __syncthreads();
    for (int s = 128; s > 0; s >>= 1) {
        if (tid < s) {
            smn[tid] = fminf(smn[tid], smn[tid + s]);
            smx[tid] = fmaxf(smx[tid], smx[tid + s]);
        }
        __syncthreads();
    }

    // ---- pairwise exchange + params (thread 0) ----
    if (tid == 0) {
        __hip_atomic_store(&part[chan * 4 + half * 2 + 0], smn[0],
                           __ATOMIC_RELAXED, __HIP_MEMORY_SCOPE_AGENT);
        __hip_atomic_store(&part[chan * 4 + half * 2 + 1], smx[0],
                           __ATOMIC_RELAXED, __HIP_MEMORY_SCOPE_AGENT);
        __hip_atomic_fetch_add(&cnt[chan], 1,
                               __ATOMIC_RELEASE, __HIP_MEMORY_SCOPE_AGENT);
        while (__hip_atomic_load(&cnt[chan], __ATOMIC_ACQUIRE,
                                 __HIP_MEMORY_SCOPE_AGENT) < 2)
            __builtin_amdgcn_s_sleep(2);

        const float amn = __hip_atomic_load(&part[chan * 4 + 0], __ATOMIC_RELAXED, __HIP_MEMORY_SCOPE_AGENT);
        const float amx = __hip_atomic_load(&part[chan * 4 + 1], __ATOMIC_RELAXED, __HIP_MEMORY_SCOPE_AGENT);
        const float bmn = __hip_atomic_load(&part[chan * 4 + 2], __ATOMIC_RELAXED, __HIP_MEMORY_SCOPE_AGENT);
        const float bmx = __hip_atomic_load(&part[chan * 4 + 3], __ATOMIC_RELAXED, __HIP_MEMORY_SCOPE_AGENT);
        const float cmn = fminf(amn, bmn);
        const float cmx = fmaxf(amx, bmx);
        const float range = sub_rn(cmx, cmn);

        float pos[RNUM - 1];
        #pragma unroll
        for (int i = 0; i < RNUM - 1; ++i)
            pos[i] = add_rn(mul_rn(region_percentiles[chan * (RNUM - 1) + i], range), cmn);
        for (int i = 1; i < RNUM - 1; ++i) {   // insertion sort, 7 elems
            float v = pos[i];
            int j = i - 1;
            while (j >= 0 && pos[j] > v) { pos[j + 1] = pos[j]; --j; }
            pos[j + 1] = v;
        }
        #pragma unroll
        for (int i = 0; i < RNUM - 1; ++i) sprm[i] = pos[i];
        #pragma unroll
        for (int i = 0; i < RNUM; ++i) {
            const float left  = (i == 0)        ? cmn : pos[i - 1];
            const float right = (i == RNUM - 1) ? add_rn(cmx, 1e-6f) : pos[i];
            sprm[RNUM - 1 + i] = add_rn(left,
                                        mul_rn(proxy_percentiles[chan * RNUM + i],
                                               sub_rn(right, left)));
        }
    }
    __syncthreads();

    const float b0 = sprm[0], b1 = sprm[1], b2 = sprm[2], b3 = sprm[3];
    const float b4 = sprm[4], b5 = sprm[5], b6 = sprm[6];
    const float r0 = sprm[7],  r1 = sprm[8],  r2 = sprm[9],  r3 = sprm[10];
    const float r4 = sprm[11], r5 = sprm[12], r6 = sprm[13], r7 = sprm[14];

    // ---- phase 2: transform. Unheld first (L3-hot), then LDS, then regs.
    // NT stores: out is never re-read.
    #pragma unroll
    for (int j = 0; j < NUNH; ++j) {
        const int idx = (NREG + NLDS + j) * 256 + tid;
        const f32x4 v = px[idx];
        f32x4 o;
        o.x = bst_sel(v.x, b0,b1,b2,b3,b4,b5,b6, r0,r1,r2,r3,r4,r5,r6,r7);
        o.y = bst_sel(v.y, b0,b1,b2,b3,b4,b5,b6, r0,r1,r2,r3,r4,r5,r6,r7);
        o.z = bst_sel(v.z, b0,b1,b2,b3,b4,b5,b6, r0,r1,r2,r3,r4,r5,r6,r7);
        o.w = bst_sel(v.w, b0,b1,b2,b3,b4,b5,b6, r0,r1,r2,r3,r4,r5,r6,r7);
        __builtin_nontemporal_store(o, &po[idx]);
    }
    #pragma unroll
    for (int j = 0; j < NLDS; ++j) {
        const f32x4 v = slds[j * 256 + tid];
        f32x4 o;
        o.x = bst_sel(v.x, b0,b1,b2,b3,b4,b5,b6, r0,r1,r2,r3,r4,r5,r6,r7);
        o.y = bst_sel(v.y, b0,b1,b2,b3,b4,b5,b6, r0,r1,r2,r3,r4,r5,r6,r7);
        o.z = bst_sel(v.z, b0,b1,b2,b3,b4,b5,b6, r0,r1,r2,r3,r4,r5,r6,r7);
        o.w = bst_sel(v.w, b0,b1,b2,b3,b4,b5,b6, r0,r1,r2,r3,r4,r5,r6,r7);
        __builtin_nontemporal_store(o, &po[(NREG + j) * 256 + tid]);
    }
    #pragma unroll
    for (int k = 0; k < NREG; ++k) {
        const f32x4 v = h[k];
        f32x4 o;
        o.x = bst_sel(v.x, b0,b1,b2,b3,b4,b5,b6, r0,r1,r2,r3,r4,r5,r6,r7);
        o.y = bst_sel(v.y, b0,b1,b2,b3,b4,b5,b6, r0,r1,r2,r3,r4,r5,r6,r7);
        o.z = bst_sel(v.z, b0,b1,b2,b3,b4,b5,b6, r0,r1,r2,r3,r4,r5,r6,r7);
        o.w = bst_sel(v.w, b0,b1,b2,b3,b4,b5,b6, r0,r1,r2,r3,r4,r5,r6,r7);
        __builtin_nontemporal_store(o, &po[k * 256 + tid]);
    }
}

// ---------------------------------------------------------------------------
extern "C" void kernel_launch(void* const* d_in, const int* in_sizes, int n_in,
                              void* d_out, int out_size, void* d_ws, size_t ws_size,
                              hipStream_t stream) {
    const float* x  = (const float*)d_in[0];
    const float* rp = (const float*)d_in[1];
    const float* pp = (const float*)d_in[2];
    float* out = (float*)d_out;

    int*   cnt  = (int*)d_ws;                      // 192 counters (zeroed below)
    float* part = (float*)((char*)d_ws + 1024);    // 192 x 4 floats

    // zero the pair-arrival counters each launch (capture-legal memset node)
    hipMemsetAsync(d_ws, 0, 1024, stream);

    k_fused<<<CCH * 2, 256, 0, stream>>>(x, rp, pp, out, cnt, part);
}

// Round 10
// 190.473 us; speedup vs baseline: 1.0223x; 1.0223x over previous
//
#include <hip/hip_runtime.h>
#include <math.h>

#pragma clang fp contract(off)

// Problem constants
#define CCH   192              // B*c
#define HW    (512*512)
#define RNUM  8
#define SUB   8                // blocks per channel
#define X4_PER_CH (HW / 4)     // 65536 f32x4 per channel
#define SLAB  (X4_PER_CH / SUB)// 8192 f32x4 per block
#define PT    (SLAB / 256)     // 32 f32x4 per thread
#define NREG  16               // held in registers (64 VGPRs)
#define NLDS  8                // held in LDS (32 KiB/block, private slots)
#define NUNH  (PT - NREG - NLDS) // 8 unheld -> re-read (L3-hot)

typedef float f32x4 __attribute__((ext_vector_type(4)));

// ---------------------------------------------------------------------------
// Un-contractible fp32 RN ops (HIP's __f*_rn are contractable; default
// -ffp-contract fused mul+add in round 1 -> region flips). absmax==0.0
// confirmed rounds 4-8 with these.
// ---------------------------------------------------------------------------
__device__ __forceinline__ float mul_rn(float a, float b) {
    float r; asm volatile("v_mul_f32 %0, %1, %2" : "=v"(r) : "v"(a), "v"(b)); return r;
}
__device__ __forceinline__ float add_rn(float a, float b) {
    float r; asm volatile("v_add_f32 %0, %1, %2" : "=v"(r) : "v"(a), "v"(b)); return r;
}
__device__ __forceinline__ float sub_rn(float a, float b) {
    float r; asm volatile("v_sub_f32 %0, %1, %2" : "=v"(r) : "v"(a), "v"(b)); return r;
}

// region-value select: id = count(b_i <= v) -> BST, 7 v_cmp + 7 v_cndmask.
__device__ __forceinline__ float bst_sel(float v,
    float b0, float b1, float b2, float b3, float b4, float b5, float b6,
    float r0, float r1, float r2, float r3, float r4, float r5, float r6, float r7) {
    return (v < b3) ? ((v < b1) ? ((v < b0) ? r0 : r1)
                                : ((v < b2) ? r2 : r3))
                    : ((v < b5) ? ((v < b4) ? r4 : r5)
                                : ((v < b6) ? r6 : r7));
}

// ---------------------------------------------------------------------------
// Fused kernel, 8 blocks/channel, 4 blocks/CU (VGPR<=128 via launch_bounds).
// Each block: load slab once (16 f32x4/thread regs + 8 LDS + 8 unheld),
// block min/max, 8-way channel sync via ws atomics, params (bit-identical
// in all 8 blocks), transform held data, re-read only the unheld 25%
// (freshest lines -> L3 hit). NT stores keep the write stream from
// evicting x.
// Deadlock-safe: 4 blocks/CU * 256 CU = 1024 co-resident blocks = channels
// 0..127 fully resident at start; groups contiguous in dispatch order, so a
// complete group is always resident and progress is guaranteed.
// ---------------------------------------------------------------------------
__global__ __launch_bounds__(256, 4) void k_fused(
        const float* __restrict__ xg,
        const float* __restrict__ region_percentiles,
        const float* __restrict__ proxy_percentiles,
        float* __restrict__ outg,
        int*   __restrict__ cnt,    // ws: per-channel arrival counters (memset 0)
        float* __restrict__ part) { // ws: per-channel 8x{mn,mx}
    const int tid  = threadIdx.x;
    const int chan = blockIdx.x / SUB;
    const int sub  = blockIdx.x % SUB;

    const f32x4* px = (const f32x4*)xg + (size_t)chan * X4_PER_CH + (size_t)sub * SLAB;
    f32x4*       po = (f32x4*)outg     + (size_t)chan * X4_PER_CH + (size_t)sub * SLAB;

    __shared__ f32x4 slds[NLDS * 256];   // 32 KiB, thread-private slots
    __shared__ float smn[256], smx[256];
    __shared__ float sprm[16];

    // ---- phase 1: load once, reduce min/max ----
    f32x4 h[NREG];
    #pragma unroll
    for (int k = 0; k < NREG; ++k) h[k] = px[k * 256 + tid];

    float mn = INFINITY, mx = -INFINITY;
    #pragma unroll
    for (int k = 0; k < NREG; ++k) {
        mn = fminf(mn, fminf(fminf(h[k].x, h[k].y), fminf(h[k].z, h[k].w)));
        mx = fmaxf(mx, fmaxf(fmaxf(h[k].x, h[k].y), fmaxf(h[k].z, h[k].w)));
    }
    #pragma unroll
    for (int j = 0; j < NLDS; ++j) {
        f32x4 t = px[(NREG + j) * 256 + tid];
        mn = fminf(mn, fminf(fminf(t.x, t.y), fminf(t.z, t.w)));
        mx = fmaxf(mx, fmaxf(fmaxf(t.x, t.y), fmaxf(t.z, t.w)));
        slds[j * 256 + tid] = t;   // own slot; no barrier needed
    }
    // unheld tail loaded LAST -> newest lines in L3 when re-read first below
    #pragma unroll
    for (int j = 0; j < NUNH; ++j) {
        f32x4 t = px[(NREG + NLDS + j) * 256 + tid];
        mn = fminf(mn, fminf(fminf(t.x, t.y), fminf(t.z, t.w)));
        mx = fmaxf(mx, fmaxf(fmaxf(t.x, t.y), fmaxf(t.z, t.w)));
    }

    smn[tid] = mn; smx[tid] = mx;
    __syncthreads();
    for (int s = 128; s > 0; s >>= 1) {
        if (tid < s) {
            smn[tid] = fminf(smn[tid], smn[tid + s]);
            smx[tid] = fmaxf(smx[tid], smx[tid + s]);
        }
        __syncthreads();
    }

    // ---- 8-way channel sync + params (thread 0, bit-identical per block) ----
    if (tid == 0) {
        __hip_atomic_store(&part[chan * 16 + sub * 2 + 0], smn[0],
                           __ATOMIC_RELAXED, __HIP_MEMORY_SCOPE_AGENT);
        __hip_atomic_store(&part[chan * 16 + sub * 2 + 1], smx[0],
                           __ATOMIC_RELAXED, __HIP_MEMORY_SCOPE_AGENT);
        __hip_atomic_fetch_add(&cnt[chan], 1,
                               __ATOMIC_RELEASE, __HIP_MEMORY_SCOPE_AGENT);
        while (__hip_atomic_load(&cnt[chan], __ATOMIC_ACQUIRE,
                                 __HIP_MEMORY_SCOPE_AGENT) < SUB)
            __builtin_amdgcn_s_sleep(2);

        float cmn = INFINITY, cmx = -INFINITY;
        #pragma unroll
        for (int p = 0; p < SUB; ++p) {
            cmn = fminf(cmn, __hip_atomic_load(&part[chan * 16 + p * 2 + 0],
                              __ATOMIC_RELAXED, __HIP_MEMORY_SCOPE_AGENT));
            cmx = fmaxf(cmx, __hip_atomic_load(&part[chan * 16 + p * 2 + 1],
                              __ATOMIC_RELAXED, __HIP_MEMORY_SCOPE_AGENT));
        }
        const float range = sub_rn(cmx, cmn);

        float pos[RNUM - 1];
        #pragma unroll
        for (int i = 0; i < RNUM - 1; ++i)
            pos[i] = add_rn(mul_rn(region_percentiles[chan * (RNUM - 1) + i], range), cmn);
        for (int i = 1; i < RNUM - 1; ++i) {   // insertion sort, 7 elems
            float v = pos[i];
            int j = i - 1;
            while (j >= 0 && pos[j] > v) { pos[j + 1] = pos[j]; --j; }
            pos[j + 1] = v;
        }
        #pragma unroll
        for (int i = 0; i < RNUM - 1; ++i) sprm[i] = pos[i];
        #pragma unroll
        for (int i = 0; i < RNUM; ++i) {
            const float left  = (i == 0)        ? cmn : pos[i - 1];
            const float right = (i == RNUM - 1) ? add_rn(cmx, 1e-6f) : pos[i];
            sprm[RNUM - 1 + i] = add_rn(left,
                                        mul_rn(proxy_percentiles[chan * RNUM + i],
                                               sub_rn(right, left)));
        }
    }
    __syncthreads();

    const float b0 = sprm[0], b1 = sprm[1], b2 = sprm[2], b3 = sprm[3];
    const float b4 = sprm[4], b5 = sprm[5], b6 = sprm[6];
    const float r0 = sprm[7],  r1 = sprm[8],  r2 = sprm[9],  r3 = sprm[10];
    const float r4 = sprm[11], r5 = sprm[12], r6 = sprm[13], r7 = sprm[14];

    // ---- phase 2: unheld first (L3-hottest), then LDS, then registers ----
    #pragma unroll
    for (int j = 0; j < NUNH; ++j) {
        const int idx = (NREG + NLDS + j) * 256 + tid;
        const f32x4 v = px[idx];
        f32x4 o;
        o.x = bst_sel(v.x, b0,b1,b2,b3,b4,b5,b6, r0,r1,r2,r3,r4,r5,r6,r7);
        o.y = bst_sel(v.y, b0,b1,b2,b3,b4,b5,b6, r0,r1,r2,r3,r4,r5,r6,r7);
        o.z = bst_sel(v.z, b0,b1,b2,b3,b4,b5,b6, r0,r1,r2,r3,r4,r5,r6,r7);
        o.w = bst_sel(v.w, b0,b1,b2,b3,b4,b5,b6, r0,r1,r2,r3,r4,r5,r6,r7);
        __builtin_nontemporal_store(o, &po[idx]);
    }
    #pragma unroll
    for (int j = 0; j < NLDS; ++j) {
        const f32x4 v = slds[j * 256 + tid];
        f32x4 o;
        o.x = bst_sel(v.x, b0,b1,b2,b3,b4,b5,b6, r0,r1,r2,r3,r4,r5,r6,r7);
        o.y = bst_sel(v.y, b0,b1,b2,b3,b4,b5,b6, r0,r1,r2,r3,r4,r5,r6,r7);
        o.z = bst_sel(v.z, b0,b1,b2,b3,b4,b5,b6, r0,r1,r2,r3,r4,r5,r6,r7);
        o.w = bst_sel(v.w, b0,b1,b2,b3,b4,b5,b6, r0,r1,r2,r3,r4,r5,r6,r7);
        __builtin_nontemporal_store(o, &po[(NREG + j) * 256 + tid]);
    }
    #pragma unroll
    for (int k = 0; k < NREG; ++k) {
        const f32x4 v = h[k];
        f32x4 o;
        o.x = bst_sel(v.x, b0,b1,b2,b3,b4,b5,b6, r0,r1,r2,r3,r4,r5,r6,r7);
        o.y = bst_sel(v.y, b0,b1,b2,b3,b4,b5,b6, r0,r1,r2,r3,r4,r5,r6,r7);
        o.z = bst_sel(v.z, b0,b1,b2,b3,b4,b5,b6, r0,r1,r2,r3,r4,r5,r6,r7);
        o.w = bst_sel(v.w, b0,b1,b2,b3,b4,b5,b6, r0,r1,r2,r3,r4,r5,r6,r7);
        __builtin_nontemporal_store(o, &po[k * 256 + tid]);
    }
}

// ---------------------------------------------------------------------------
extern "C" void kernel_launch(void* const* d_in, const int* in_sizes, int n_in,
                              void* d_out, int out_size, void* d_ws, size_t ws_size,
                              hipStream_t stream) {
    const float* x  = (const float*)d_in[0];
    const float* rp = (const float*)d_in[1];
    const float* pp = (const float*)d_in[2];
    float* out = (float*)d_out;

    int*   cnt  = (int*)d_ws;                    // 192 counters
    float* part = (float*)((char*)d_ws + 1024);  // 192 x 16 floats

    // zero arrival counters each launch (capture-legal memset node)
    hipMemsetAsync(d_ws, 0, 1024, stream);

    k_fused<<<CCH * SUB, 256, 0, stream>>>(x, rp, pp, out, cnt, part);
}

// Round 12
// 141.186 us; speedup vs baseline: 1.3791x; 1.3491x over previous
//
#include <hip/hip_runtime.h>
#include <math.h>

#pragma clang fp contract(off)

// Problem constants
#define CCH   192              // B*c
#define HW    (512*512)
#define RNUM  8
#define SUB   8                // blocks per channel
#define X4_PER_CH (HW / 4)     // 65536 f32x4 per channel
#define SLAB  (X4_PER_CH / SUB)// 8192 f32x4 per block (128 KiB)
#define PT    (SLAB / 256)     // 32 f32x4 per thread
#define NREG  16               // held in registers (64 VGPRs, PINNED)
#define NLDS  8                // held in LDS (32 KiB/block, private slots)
#define NUNH  (PT - NREG - NLDS) // 8 re-read (32 KiB/block, own-XCD L2-hot)

typedef float f32x4 __attribute__((ext_vector_type(4)));

// ---------------------------------------------------------------------------
// Un-contractible fp32 RN ops (HIP's __f*_rn are contractable; default
// -ffp-contract fused mul+add in round 1 -> region flips). absmax==0.0
// confirmed rounds 4-10 with these.
// ---------------------------------------------------------------------------
__device__ __forceinline__ float mul_rn(float a, float b) {
    float r; asm volatile("v_mul_f32 %0, %1, %2" : "=v"(r) : "v"(a), "v"(b)); return r;
}
__device__ __forceinline__ float add_rn(float a, float b) {
    float r; asm volatile("v_add_f32 %0, %1, %2" : "=v"(r) : "v"(a), "v"(b)); return r;
}
__device__ __forceinline__ float sub_rn(float a, float b) {
    float r; asm volatile("v_sub_f32 %0, %1, %2" : "=v"(r) : "v"(a), "v"(b)); return r;
}

// region-value select: id = count(b_i <= v) -> BST, 7 v_cmp + 7 v_cndmask.
__device__ __forceinline__ float bst_sel(float v,
    float b0, float b1, float b2, float b3, float b4, float b5, float b6,
    float r0, float r1, float r2, float r3, float r4, float r5, float r6, float r7) {
    return (v < b3) ? ((v < b1) ? ((v < b0) ? r0 : r1)
                                : ((v < b2) ? r2 : r3))
                    : ((v < b5) ? ((v < b4) ? r4 : r5)
                                : ((v < b6) ? r6 : r7));
}

// ---------------------------------------------------------------------------
// Fused kernel, 8 blocks/channel, 4 blocks/CU.
// Round-10 fixes (this round: fence builtin corrected to compile):
//  (a) held values OPAQUE-PINNED via asm identity -> compiler cannot
//      rematerialize the loads in phase 2 (round 10: VGPR=64 proved it
//      reloaded from global instead of holding).
//  (b) spin polls are RELAXED (coherent load, no per-poll cache
//      invalidation); ONE acquire fence after the loop (round 8/10 polled
//      with ACQUIRE -> L1/L2 invalidation storm, occupancy-independent
//      1.3-1.4 TB/s).
// Deadlock-safe: 4 blocks/CU * 256 CU = 1024 co-resident blocks >= 8, groups
// contiguous in dispatch order -> a complete channel group is always
// resident; retirement frees slots in whole-group batches.
// ---------------------------------------------------------------------------
__global__ __launch_bounds__(256, 4) void k_fused(
        const float* __restrict__ xg,
        const float* __restrict__ region_percentiles,
        const float* __restrict__ proxy_percentiles,
        float* __restrict__ outg,
        int*   __restrict__ cnt,    // ws: per-channel arrival counters (memset 0)
        float* __restrict__ part) { // ws: per-channel 8x{mn,mx}
    const int tid  = threadIdx.x;
    const int chan = blockIdx.x / SUB;
    const int sub  = blockIdx.x % SUB;

    const f32x4* px = (const f32x4*)xg + (size_t)chan * X4_PER_CH + (size_t)sub * SLAB;
    f32x4*       po = (f32x4*)outg     + (size_t)chan * X4_PER_CH + (size_t)sub * SLAB;

    __shared__ f32x4 slds[NLDS * 256];   // 32 KiB, thread-private slots
    __shared__ float smn[256], smx[256];
    __shared__ float sprm[16];

    // ---- phase 1: load once, reduce min/max ----
    float hx[NREG], hy[NREG], hz[NREG], hw[NREG];
    float mn = INFINITY, mx = -INFINITY;
    #pragma unroll
    for (int k = 0; k < NREG; ++k) {
        const f32x4 t = px[k * 256 + tid];
        hx[k] = t.x; hy[k] = t.y; hz[k] = t.z; hw[k] = t.w;
        mn = fminf(mn, fminf(fminf(t.x, t.y), fminf(t.z, t.w)));
        mx = fmaxf(mx, fmaxf(fmaxf(t.x, t.y), fmaxf(t.z, t.w)));
    }
    // OPAQUE PIN: value provenance hidden -> no remat from global in phase 2.
    #pragma unroll
    for (int k = 0; k < NREG; ++k)
        asm volatile("" : "+v"(hx[k]), "+v"(hy[k]), "+v"(hz[k]), "+v"(hw[k]));

    #pragma unroll
    for (int j = 0; j < NLDS; ++j) {
        const f32x4 t = px[(NREG + j) * 256 + tid];
        mn = fminf(mn, fminf(fminf(t.x, t.y), fminf(t.z, t.w)));
        mx = fmaxf(mx, fmaxf(fmaxf(t.x, t.y), fmaxf(t.z, t.w)));
        slds[j * 256 + tid] = t;   // own slot; no barrier needed
    }
    // unheld tail loaded LAST -> hottest lines in own XCD's L2 at re-read
    #pragma unroll
    for (int j = 0; j < NUNH; ++j) {
        const f32x4 t = px[(NREG + NLDS + j) * 256 + tid];
        mn = fminf(mn, fminf(fminf(t.x, t.y), fminf(t.z, t.w)));
        mx = fmaxf(mx, fmaxf(fmaxf(t.x, t.y), fmaxf(t.z, t.w)));
    }

    smn[tid] = mn; smx[tid] = mx;
    __syncthreads();
    for (int s = 128; s > 0; s >>= 1) {
        if (tid < s) {
            smn[tid] = fminf(smn[tid], smn[tid + s]);
            smx[tid] = fmaxf(smx[tid], smx[tid + s]);
        }
        __syncthreads();
    }

    // ---- 8-way channel sync + params (thread 0, bit-identical per block) ----
    if (tid == 0) {
        __hip_atomic_store(&part[chan * 16 + sub * 2 + 0], smn[0],
                           __ATOMIC_RELAXED, __HIP_MEMORY_SCOPE_AGENT);
        __hip_atomic_store(&part[chan * 16 + sub * 2 + 1], smx[0],
                           __ATOMIC_RELAXED, __HIP_MEMORY_SCOPE_AGENT);
        __hip_atomic_fetch_add(&cnt[chan], 1,
                               __ATOMIC_RELEASE, __HIP_MEMORY_SCOPE_AGENT);
        // RELAXED polls: coherent loads, no invalidation per iteration.
        while (__hip_atomic_load(&cnt[chan], __ATOMIC_RELAXED,
                                 __HIP_MEMORY_SCOPE_AGENT) < SUB)
            __builtin_amdgcn_s_sleep(8);
        // One acquire fence total: order the part[] reads below.
        __builtin_amdgcn_fence(__ATOMIC_ACQUIRE, "agent");

        float cmn = INFINITY, cmx = -INFINITY;
        #pragma unroll
        for (int p = 0; p < SUB; ++p) {
            cmn = fminf(cmn, __hip_atomic_load(&part[chan * 16 + p * 2 + 0],
                              __ATOMIC_RELAXED, __HIP_MEMORY_SCOPE_AGENT));
            cmx = fmaxf(cmx, __hip_atomic_load(&part[chan * 16 + p * 2 + 1],
                              __ATOMIC_RELAXED, __HIP_MEMORY_SCOPE_AGENT));
        }
        const float range = sub_rn(cmx, cmn);

        float pos[RNUM - 1];
        #pragma unroll
        for (int i = 0; i < RNUM - 1; ++i)
            pos[i] = add_rn(mul_rn(region_percentiles[chan * (RNUM - 1) + i], range), cmn);
        for (int i = 1; i < RNUM - 1; ++i) {   // insertion sort, 7 elems
            float v = pos[i];
            int j = i - 1;
            while (j >= 0 && pos[j] > v) { pos[j + 1] = pos[j]; --j; }
            pos[j + 1] = v;
        }
        #pragma unroll
        for (int i = 0; i < RNUM - 1; ++i) sprm[i] = pos[i];
        #pragma unroll
        for (int i = 0; i < RNUM; ++i) {
            const float left  = (i == 0)        ? cmn : pos[i - 1];
            const float right = (i == RNUM - 1) ? add_rn(cmx, 1e-6f) : pos[i];
            sprm[RNUM - 1 + i] = add_rn(left,
                                        mul_rn(proxy_percentiles[chan * RNUM + i],
                                               sub_rn(right, left)));
        }
    }
    __syncthreads();

    const float b0 = sprm[0], b1 = sprm[1], b2 = sprm[2], b3 = sprm[3];
    const float b4 = sprm[4], b5 = sprm[5], b6 = sprm[6];
    const float r0 = sprm[7],  r1 = sprm[8],  r2 = sprm[9],  r3 = sprm[10];
    const float r4 = sprm[11], r5 = sprm[12], r6 = sprm[13], r7 = sprm[14];

    // ---- phase 2: unheld first (L2-hottest), then LDS, then registers ----
    #pragma unroll
    for (int j = 0; j < NUNH; ++j) {
        const int idx = (NREG + NLDS + j) * 256 + tid;
        const f32x4 v = px[idx];
        f32x4 o;
        o.x = bst_sel(v.x, b0,b1,b2,b3,b4,b5,b6, r0,r1,r2,r3,r4,r5,r6,r7);
        o.y = bst_sel(v.y, b0,b1,b2,b3,b4,b5,b6, r0,r1,r2,r3,r4,r5,r6,r7);
        o.z = bst_sel(v.z, b0,b1,b2,b3,b4,b5,b6, r0,r1,r2,r3,r4,r5,r6,r7);
        o.w = bst_sel(v.w, b0,b1,b2,b3,b4,b5,b6, r0,r1,r2,r3,r4,r5,r6,r7);
        __builtin_nontemporal_store(o, &po[idx]);
    }
    #pragma unroll
    for (int j = 0; j < NLDS; ++j) {
        const f32x4 v = slds[j * 256 + tid];
        f32x4 o;
        o.x = bst_sel(v.x, b0,b1,b2,b3,b4,b5,b6, r0,r1,r2,r3,r4,r5,r6,r7);
        o.y = bst_sel(v.y, b0,b1,b2,b3,b4,b5,b6, r0,r1,r2,r3,r4,r5,r6,r7);
        o.z = bst_sel(v.z, b0,b1,b2,b3,b4,b5,b6, r0,r1,r2,r3,r4,r5,r6,r7);
        o.w = bst_sel(v.w, b0,b1,b2,b3,b4,b5,b6, r0,r1,r2,r3,r4,r5,r6,r7);
        __builtin_nontemporal_store(o, &po[(NREG + j) * 256 + tid]);
    }
    #pragma unroll
    for (int k = 0; k < NREG; ++k) {
        f32x4 o;
        o.x = bst_sel(hx[k], b0,b1,b2,b3,b4,b5,b6, r0,r1,r2,r3,r4,r5,r6,r7);
        o.y = bst_sel(hy[k], b0,b1,b2,b3,b4,b5,b6, r0,r1,r2,r3,r4,r5,r6,r7);
        o.z = bst_sel(hz[k], b0,b1,b2,b3,b4,b5,b6, r0,r1,r2,r3,r4,r5,r6,r7);
        o.w = bst_sel(hw[k], b0,b1,b2,b3,b4,b5,b6, r0,r1,r2,r3,r4,r5,r6,r7);
        __builtin_nontemporal_store(o, &po[k * 256 + tid]);
    }
}

// ---------------------------------------------------------------------------
extern "C" void kernel_launch(void* const* d_in, const int* in_sizes, int n_in,
                              void* d_out, int out_size, void* d_ws, size_t ws_size,
                              hipStream_t stream) {
    const float* x  = (const float*)d_in[0];
    const float* rp = (const float*)d_in[1];
    const float* pp = (const float*)d_in[2];
    float* out = (float*)d_out;

    int*   cnt  = (int*)d_ws;                    // 192 counters
    float* part = (float*)((char*)d_ws + 1024);  // 192 x 16 floats

    // zero arrival counters each launch (capture-legal memset node)
    (void)hipMemsetAsync(d_ws, 0, 1024, stream);

    k_fused<<<CCH * SUB, 256, 0, stream>>>(x, rp, pp, out, cnt, part);
}

// Round 13
// 114.727 us; speedup vs baseline: 1.6972x; 1.2306x over previous
//
#include <hip/hip_runtime.h>
#include <math.h>

#pragma clang fp contract(off)

// Problem constants
#define CCH   192              // B*c
#define HW    (512*512)
#define RNUM  8
#define SUB   4                // blocks per channel -> grid 768 <= 1024 capacity
#define X4_PER_CH (HW / 4)     // 65536 f32x4 per channel
#define SLAB  (X4_PER_CH / SUB)// 16384 f32x4 per block (256 KiB)
#define PT    (SLAB / 256)     // 64 f32x4 per thread
#define NREG  16               // held in registers/AGPRs (64 regs, PINNED)
#define NLDS  9                // held in LDS (36 KiB/block, private slots)
#define NUNH  (PT - NREG - NLDS) // 39 re-read -> L3-resident by design

typedef float f32x4 __attribute__((ext_vector_type(4)));

// ---------------------------------------------------------------------------
// Un-contractible fp32 RN ops (HIP's __f*_rn are contractable; default
// -ffp-contract fused mul+add in round 1 -> region flips). absmax==0.0
// confirmed rounds 4-12 with these.
// ---------------------------------------------------------------------------
__device__ __forceinline__ float mul_rn(float a, float b) {
    float r; asm volatile("v_mul_f32 %0, %1, %2" : "=v"(r) : "v"(a), "v"(b)); return r;
}
__device__ __forceinline__ float add_rn(float a, float b) {
    float r; asm volatile("v_add_f32 %0, %1, %2" : "=v"(r) : "v"(a), "v"(b)); return r;
}
__device__ __forceinline__ float sub_rn(float a, float b) {
    float r; asm volatile("v_sub_f32 %0, %1, %2" : "=v"(r) : "v"(a), "v"(b)); return r;
}

// region-value select: id = count(b_i <= v) -> BST, 7 v_cmp + 7 v_cndmask.
__device__ __forceinline__ float bst_sel(float v,
    float b0, float b1, float b2, float b3, float b4, float b5, float b6,
    float r0, float r1, float r2, float r3, float r4, float r5, float r6, float r7) {
    return (v < b3) ? ((v < b1) ? ((v < b0) ? r0 : r1)
                                : ((v < b2) ? r2 : r3))
                    : ((v < b5) ? ((v < b4) ? r4 : r5)
                                : ((v < b6) ? r6 : r7));
}

// ---------------------------------------------------------------------------
// Fused kernel, 4 blocks/channel, grid 768 <= co-residency capacity 1024
// (round 12's 195us/dispatch was the retirement convoy: grid 1536 > 1024 ->
// tail channels' blocks dribbled in one retirement at a time, each spinning
// in a slot waiting for group completion; 1.6 TB/s, VALU 8%, stall-bound).
// With ALL blocks resident from t=0 the group sync costs only dispatch skew.
//
// Phase-1 read order is the eviction shield: held-in-reg section read FIRST
// (oldest LRU lines -> evicted by the write stream, but never re-read),
// unheld tail read LAST (newest -> survives; re-read hits L3: 201 MB of x
// fits the 268 MB MALL at the sync point).
// ---------------------------------------------------------------------------
__global__ __launch_bounds__(256, 4) void k_fused(
        const float* __restrict__ xg,
        const float* __restrict__ region_percentiles,
        const float* __restrict__ proxy_percentiles,
        float* __restrict__ outg,
        int*   __restrict__ cnt,    // ws: per-channel arrival counters (memset 0)
        float* __restrict__ part) { // ws: per-channel SUB x {mn,mx}
    const int tid  = threadIdx.x;
    const int chan = blockIdx.x / SUB;
    const int sub  = blockIdx.x % SUB;

    const f32x4* px = (const f32x4*)xg + (size_t)chan * X4_PER_CH + (size_t)sub * SLAB;
    f32x4*       po = (f32x4*)outg     + (size_t)chan * X4_PER_CH + (size_t)sub * SLAB;

    __shared__ f32x4 slds[NLDS * 256];   // 36 KiB, thread-private slots
    __shared__ float smn[256], smx[256];
    __shared__ float sprm[16];

    // ---- phase 1: load once, reduce min/max ----
    float hx[NREG], hy[NREG], hz[NREG], hw[NREG];
    float mn = INFINITY, mx = -INFINITY;
    #pragma unroll
    for (int k = 0; k < NREG; ++k) {
        const f32x4 t = px[k * 256 + tid];
        hx[k] = t.x; hy[k] = t.y; hz[k] = t.z; hw[k] = t.w;
        mn = fminf(mn, fminf(fminf(t.x, t.y), fminf(t.z, t.w)));
        mx = fmaxf(mx, fmaxf(fmaxf(t.x, t.y), fmaxf(t.z, t.w)));
    }
    // OPAQUE PIN: provenance hidden -> no remat from global in phase 2.
    #pragma unroll
    for (int k = 0; k < NREG; ++k)
        asm volatile("" : "+v"(hx[k]), "+v"(hy[k]), "+v"(hz[k]), "+v"(hw[k]));

    #pragma unroll
    for (int j = 0; j < NLDS; ++j) {
        const f32x4 t = px[(NREG + j) * 256 + tid];
        mn = fminf(mn, fminf(fminf(t.x, t.y), fminf(t.z, t.w)));
        mx = fmaxf(mx, fmaxf(fmaxf(t.x, t.y), fmaxf(t.z, t.w)));
        slds[j * 256 + tid] = t;   // own slot; no barrier needed
    }
    // unheld tail loaded LAST -> newest LRU lines at the sync point
    #pragma unroll 8
    for (int j = 0; j < NUNH; ++j) {
        const f32x4 t = px[(NREG + NLDS + j) * 256 + tid];
        mn = fminf(mn, fminf(fminf(t.x, t.y), fminf(t.z, t.w)));
        mx = fmaxf(mx, fmaxf(fmaxf(t.x, t.y), fmaxf(t.z, t.w)));
    }

    smn[tid] = mn; smx[tid] = mx;
    __syncthreads();
    for (int s = 128; s > 0; s >>= 1) {
        if (tid < s) {
            smn[tid] = fminf(smn[tid], smn[tid + s]);
            smx[tid] = fmaxf(smx[tid], smx[tid + s]);
        }
        __syncthreads();
    }

    // ---- SUB-way channel sync + params (thread 0, bit-identical per block) ----
    if (tid == 0) {
        __hip_atomic_store(&part[chan * 16 + sub * 2 + 0], smn[0],
                           __ATOMIC_RELAXED, __HIP_MEMORY_SCOPE_AGENT);
        __hip_atomic_store(&part[chan * 16 + sub * 2 + 1], smx[0],
                           __ATOMIC_RELAXED, __HIP_MEMORY_SCOPE_AGENT);
        __hip_atomic_fetch_add(&cnt[chan], 1,
                               __ATOMIC_RELEASE, __HIP_MEMORY_SCOPE_AGENT);
        // RELAXED polls (no per-poll invalidation); one acquire fence after.
        while (__hip_atomic_load(&cnt[chan], __ATOMIC_RELAXED,
                                 __HIP_MEMORY_SCOPE_AGENT) < SUB)
            __builtin_amdgcn_s_sleep(8);
        __builtin_amdgcn_fence(__ATOMIC_ACQUIRE, "agent");

        float cmn = INFINITY, cmx = -INFINITY;
        #pragma unroll
        for (int p = 0; p < SUB; ++p) {
            cmn = fminf(cmn, __hip_atomic_load(&part[chan * 16 + p * 2 + 0],
                              __ATOMIC_RELAXED, __HIP_MEMORY_SCOPE_AGENT));
            cmx = fmaxf(cmx, __hip_atomic_load(&part[chan * 16 + p * 2 + 1],
                              __ATOMIC_RELAXED, __HIP_MEMORY_SCOPE_AGENT));
        }
        const float range = sub_rn(cmx, cmn);

        float pos[RNUM - 1];
        #pragma unroll
        for (int i = 0; i < RNUM - 1; ++i)
            pos[i] = add_rn(mul_rn(region_percentiles[chan * (RNUM - 1) + i], range), cmn);
        for (int i = 1; i < RNUM - 1; ++i) {   // insertion sort, 7 elems
            float v = pos[i];
            int j = i - 1;
            while (j >= 0 && pos[j] > v) { pos[j + 1] = pos[j]; --j; }
            pos[j + 1] = v;
        }
        #pragma unroll
        for (int i = 0; i < RNUM - 1; ++i) sprm[i] = pos[i];
        #pragma unroll
        for (int i = 0; i < RNUM; ++i) {
            const float left  = (i == 0)        ? cmn : pos[i - 1];
            const float right = (i == RNUM - 1) ? add_rn(cmx, 1e-6f) : pos[i];
            sprm[RNUM - 1 + i] = add_rn(left,
                                        mul_rn(proxy_percentiles[chan * RNUM + i],
                                               sub_rn(right, left)));
        }
    }
    __syncthreads();

    const float b0 = sprm[0], b1 = sprm[1], b2 = sprm[2], b3 = sprm[3];
    const float b4 = sprm[4], b5 = sprm[5], b6 = sprm[6];
    const float r0 = sprm[7],  r1 = sprm[8],  r2 = sprm[9],  r3 = sprm[10];
    const float r4 = sprm[11], r5 = sprm[12], r6 = sprm[13], r7 = sprm[14];

    // ---- phase 2: unheld first (L3-resident), then LDS, then registers ----
    #pragma unroll 8
    for (int j = 0; j < NUNH; ++j) {
        const int idx = (NREG + NLDS + j) * 256 + tid;
        const f32x4 v = px[idx];
        f32x4 o;
        o.x = bst_sel(v.x, b0,b1,b2,b3,b4,b5,b6, r0,r1,r2,r3,r4,r5,r6,r7);
        o.y = bst_sel(v.y, b0,b1,b2,b3,b4,b5,b6, r0,r1,r2,r3,r4,r5,r6,r7);
        o.z = bst_sel(v.z, b0,b1,b2,b3,b4,b5,b6, r0,r1,r2,r3,r4,r5,r6,r7);
        o.w = bst_sel(v.w, b0,b1,b2,b3,b4,b5,b6, r0,r1,r2,r3,r4,r5,r6,r7);
        __builtin_nontemporal_store(o, &po[idx]);
    }
    #pragma unroll
    for (int j = 0; j < NLDS; ++j) {
        const f32x4 v = slds[j * 256 + tid];
        f32x4 o;
        o.x = bst_sel(v.x, b0,b1,b2,b3,b4,b5,b6, r0,r1,r2,r3,r4,r5,r6,r7);
        o.y = bst_sel(v.y, b0,b1,b2,b3,b4,b5,b6, r0,r1,r2,r3,r4,r5,r6,r7);
        o.z = bst_sel(v.z, b0,b1,b2,b3,b4,b5,b6, r0,r1,r2,r3,r4,r5,r6,r7);
        o.w = bst_sel(v.w, b0,b1,b2,b3,b4,b5,b6, r0,r1,r2,r3,r4,r5,r6,r7);
        __builtin_nontemporal_store(o, &po[(NREG + j) * 256 + tid]);
    }
    #pragma unroll
    for (int k = 0; k < NREG; ++k) {
        f32x4 o;
        o.x = bst_sel(hx[k], b0,b1,b2,b3,b4,b5,b6, r0,r1,r2,r3,r4,r5,r6,r7);
        o.y = bst_sel(hy[k], b0,b1,b2,b3,b4,b5,b6, r0,r1,r2,r3,r4,r5,r6,r7);
        o.z = bst_sel(hz[k], b0,b1,b2,b3,b4,b5,b6, r0,r1,r2,r3,r4,r5,r6,r7);
        o.w = bst_sel(hw[k], b0,b1,b2,b3,b4,b5,b6, r0,r1,r2,r3,r4,r5,r6,r7);
        __builtin_nontemporal_store(o, &po[k * 256 + tid]);
    }
}

// ---------------------------------------------------------------------------
extern "C" void kernel_launch(void* const* d_in, const int* in_sizes, int n_in,
                              void* d_out, int out_size, void* d_ws, size_t ws_size,
                              hipStream_t stream) {
    const float* x  = (const float*)d_in[0];
    const float* rp = (const float*)d_in[1];
    const float* pp = (const float*)d_in[2];
    float* out = (float*)d_out;

    int*   cnt  = (int*)d_ws;                    // 192 counters
    float* part = (float*)((char*)d_ws + 1024);  // 192 x 16 floats

    // zero arrival counters each launch (capture-legal memset node)
    (void)hipMemsetAsync(d_ws, 0, 1024, stream);

    k_fused<<<CCH * SUB, 256, 0, stream>>>(x, rp, pp, out, cnt, part);
}